// Round 1
// baseline (42880.557 us; speedup 1.0000x reference)
//
#include <hip/hip_runtime.h>
#include <math.h>

// Problem constants (fixed by reference: x (9,256,32,32) fp32, att (9,32,32) fp32)
#define MR 1024      // m = 32*32 query locations
#define NC 8192      // n = 8*32*32 target locations
#define NCH 256      // channels
#define OT_ITERS 1000
#define IMG_STRIDE 262144  // 256*1024 floats per image

__device__ inline float wredMax(float v){
#pragma unroll
  for (int m = 32; m >= 1; m >>= 1) v = fmaxf(v, __shfl_xor(v, m, 64));
  return v;
}
__device__ inline float wredSum(float v){
#pragma unroll
  for (int m = 32; m >= 1; m >>= 1) v += __shfl_xor(v, m, 64);
  return v;
}

// K1: squared norms qq/tt, log marginals, zero-init u,v,acc
__global__ __launch_bounds__(256) void kPrep(const float* __restrict__ x,
                                             const float* __restrict__ att,
                                             float* __restrict__ qq, float* __restrict__ tt,
                                             float* __restrict__ logmu, float* __restrict__ lognu,
                                             float* __restrict__ u, float* __restrict__ v,
                                             float* __restrict__ acc){
  int idx = blockIdx.x * 256 + threadIdx.x;
  if (idx < 9216){
    int img = idx >> 10, pos = idx & 1023;
    const float* p = x + img * IMG_STRIDE + pos;
    float s = 0.f;
#pragma unroll 8
    for (int c = 0; c < NCH; ++c){ float a = p[c * 1024]; s += a * a; }
    float lg = logf(att[idx]);
    if (img == 0){ qq[idx] = s;        logmu[idx] = lg; }
    else         { tt[idx - 1024] = s; lognu[idx - 1024] = lg; }
  }
  if (idx < MR) u[idx] = 0.f;
  if (idx < NC) v[idx] = 0.f;
  if (idx == 0) *acc = 0.f;
}

// K2: M[i][j] = qq[i] + tt[j] - 2 * Q_i . T_j   (A^T*B style, both stored c-major)
__global__ __launch_bounds__(256) void kGemmM(const float* __restrict__ x,
                                              const float* __restrict__ qq,
                                              const float* __restrict__ tt,
                                              float* __restrict__ M){
  __shared__ float As[16][68];  // +4 pad: break 64-float bank stride
  __shared__ float Bs[16][68];
  int jb = blockIdx.x;              // 0..127 (column tiles of 64; never straddle image)
  int ib = blockIdx.y;              // 0..15
  int i0 = ib * 64;
  int j0 = jb * 64;
  int k  = j0 >> 10, p0 = j0 & 1023;
  const float* A = x + i0;                        // + c*1024 + i
  const float* B = x + (1 + k) * IMG_STRIDE + p0; // + c*1024 + p
  int tid = threadIdx.x;
  int lr = tid >> 4, lc = (tid & 15) * 4;
  int ty = tid >> 4, tx = tid & 15;
  float accv[4][4] = {};
  for (int kt = 0; kt < 16; ++kt){
    int c = kt * 16 + lr;
    float4 av = *(const float4*)(A + c * 1024 + lc);
    float4 bv = *(const float4*)(B + c * 1024 + lc);
    *(float4*)(&As[lr][lc]) = av;
    *(float4*)(&Bs[lr][lc]) = bv;
    __syncthreads();
#pragma unroll
    for (int kk = 0; kk < 16; ++kk){
      float4 a = *(const float4*)(&As[kk][ty * 4]);
      float4 b = *(const float4*)(&Bs[kk][tx * 4]);
      float ar[4] = {a.x, a.y, a.z, a.w};
      float br[4] = {b.x, b.y, b.z, b.w};
#pragma unroll
      for (int r = 0; r < 4; ++r)
#pragma unroll
        for (int cc = 0; cc < 4; ++cc) accv[r][cc] += ar[r] * br[cc];
    }
    __syncthreads();
  }
#pragma unroll
  for (int r = 0; r < 4; ++r){
    int i = i0 + ty * 4 + r;
    float qi = qq[i];
    float4 o;
    o.x = qi + tt[j0 + tx * 4 + 0] - 2.f * accv[r][0];
    o.y = qi + tt[j0 + tx * 4 + 1] - 2.f * accv[r][1];
    o.z = qi + tt[j0 + tx * 4 + 2] - 2.f * accv[r][2];
    o.w = qi + tt[j0 + tx * 4 + 3] - 2.f * accv[r][3];
    *(float4*)(M + (long)i * NC + j0 + tx * 4) = o;
  }
}

// K3: u[i] = logmu[i] - LSE_j(M[i][j] + v[j]); one block per row, row in registers
__global__ __launch_bounds__(256) void kUPass(const float* __restrict__ M,
                                              const float* __restrict__ v,
                                              const float* __restrict__ logmu,
                                              float* __restrict__ u){
  int row = blockIdx.x;
  int tid = threadIdx.x;
  const float* Mr = M + (long)row * NC;
  float t[32];
  float mx = -INFINITY;
#pragma unroll
  for (int kb = 0; kb < 8; ++kb){
    int cidx = kb * 1024 + tid * 4;
    float4 mv = *(const float4*)(Mr + cidx);
    float4 vv = *(const float4*)(v + cidx);
    float t0 = mv.x + vv.x, t1 = mv.y + vv.y, t2 = mv.z + vv.z, t3 = mv.w + vv.w;
    t[kb * 4 + 0] = t0; t[kb * 4 + 1] = t1; t[kb * 4 + 2] = t2; t[kb * 4 + 3] = t3;
    mx = fmaxf(mx, fmaxf(fmaxf(t0, t1), fmaxf(t2, t3)));
  }
  __shared__ float redA[4], redB[4];
  int lane = tid & 63, wid = tid >> 6;
  float wm = wredMax(mx);
  if (lane == 0) redA[wid] = wm;
  __syncthreads();
  float bm = fmaxf(fmaxf(redA[0], redA[1]), fmaxf(redA[2], redA[3]));
  float s = 0.f;
#pragma unroll
  for (int i2 = 0; i2 < 32; ++i2) s += __expf(t[i2] - bm);
  float ws = wredSum(s);
  if (lane == 0) redB[wid] = ws;
  __syncthreads();
  if (tid == 0){
    float tot = redB[0] + redB[1] + redB[2] + redB[3];
    u[row] = logmu[row] - (bm + __logf(tot));
  }
}

// K4: v[j] = lognu[j] - LSE_i(M[i][j] + u[i]); 32 columns per block, two-phase
__global__ __launch_bounds__(256) void kVPass(const float* __restrict__ M,
                                              const float* __restrict__ u,
                                              const float* __restrict__ lognu,
                                              float* __restrict__ v){
  __shared__ float ulds[1024];
  __shared__ float pm[8][32];
  __shared__ float cm[32];
  __shared__ float ps[8][32];
  int tid = threadIdx.x;
  int j0 = blockIdx.x * 32;
  int c = tid & 31, rg = tid >> 5;
  { float4 uv = *(const float4*)(u + tid * 4); *(float4*)(&ulds[tid * 4]) = uv; }
  __syncthreads();
  const float* Mp = M + j0 + c;
  float mx = -INFINITY;
  for (int r = rg; r < 1024; r += 8){
    float tv = Mp[(long)r * NC] + ulds[r];
    mx = fmaxf(mx, tv);
  }
  pm[rg][c] = mx;
  __syncthreads();
  if (tid < 32){
    float a = pm[0][tid];
#pragma unroll
    for (int q = 1; q < 8; ++q) a = fmaxf(a, pm[q][tid]);
    cm[tid] = a;
  }
  __syncthreads();
  float cmc = cm[c];
  float s = 0.f;
  for (int r = rg; r < 1024; r += 8){
    float tv = Mp[(long)r * NC] + ulds[r];
    s += __expf(tv - cmc);
  }
  ps[rg][c] = s;
  __syncthreads();
  if (tid < 32){
    float a = 0.f;
#pragma unroll
    for (int q = 0; q < 8; ++q) a += ps[q][tid];
    int j = j0 + tid;
    v[j] = lognu[j] - (cm[tid] + __logf(a));
  }
}

// K5: o = P@T rows, diff = mu*Q - o, acc += sum_i ||diff_i||_2 ; 4 rows per block
__global__ __launch_bounds__(256) void kFinal(const float* __restrict__ x,
                                              const float* __restrict__ att,
                                              const float* __restrict__ M,
                                              const float* __restrict__ u,
                                              const float* __restrict__ v,
                                              float* __restrict__ acc){
  __shared__ float pch[4][256];
  __shared__ float redS[4];
  int tid = threadIdx.x;
  int r0 = blockIdx.x * 4;
  float u4[4];
#pragma unroll
  for (int rr = 0; rr < 4; ++rr) u4[rr] = u[r0 + rr];
  float o[4] = {0.f, 0.f, 0.f, 0.f};
  for (int jc = 0; jc < NC; jc += 256){
    float vv = v[jc + tid];
#pragma unroll
    for (int rr = 0; rr < 4; ++rr)
      pch[rr][tid] = __expf(M[(long)(r0 + rr) * NC + jc + tid] + u4[rr] + vv);
    __syncthreads();
    int k = jc >> 10;
    const float* Tp = x + (1 + k) * IMG_STRIDE + tid * 1024 + (jc & 1023);
    for (int jj = 0; jj < 256; jj += 4){
      float4 tv = *(const float4*)(Tp + jj);
      float tq[4] = {tv.x, tv.y, tv.z, tv.w};
#pragma unroll
      for (int q = 0; q < 4; ++q){
        o[0] += pch[0][jj + q] * tq[q];
        o[1] += pch[1][jj + q] * tq[q];
        o[2] += pch[2][jj + q] * tq[q];
        o[3] += pch[3][jj + q] * tq[q];
      }
    }
    __syncthreads();
  }
  int lane = tid & 63, wid = tid >> 6;
  float dtot = 0.f;
#pragma unroll
  for (int rr = 0; rr < 4; ++rr){
    float mu = att[r0 + rr];
    float qv = x[tid * 1024 + (r0 + rr)];
    float diff = mu * qv - o[rr];
    float wsum = wredSum(diff * diff);
    if (lane == 0) redS[wid] = wsum;
    __syncthreads();
    if (tid == 0) dtot += sqrtf(redS[0] + redS[1] + redS[2] + redS[3]);
    __syncthreads();
  }
  if (tid == 0) atomicAdd(acc, dtot);
}

// K6: apply label/margin, write scalar output
__global__ void kOut(const float* __restrict__ acc, const int* __restrict__ label,
                     float* __restrict__ out){
  if (threadIdx.x == 0 && blockIdx.x == 0){
    float d = *acc;
    out[0] = (*label) ? d : fmaxf(0.7f - d, 0.f);
  }
}

extern "C" void kernel_launch(void* const* d_in, const int* in_sizes, int n_in,
                              void* d_out, int out_size, void* d_ws, size_t ws_size,
                              hipStream_t stream){
  const float* x   = (const float*)d_in[0];
  const float* att = (const float*)d_in[1];
  const int* label = (const int*)d_in[2];
  float* W = (float*)d_ws;
  // ws layout (floats): total ~8.42M floats = ~33.7 MB
  float* M     = W;                 // 1024*8192
  float* qq    = W + 8388608;       // 1024
  float* tt    = qq + 1024;         // 8192
  float* logmu = tt + 8192;         // 1024
  float* lognu = logmu + 1024;      // 8192
  float* u     = lognu + 8192;      // 1024
  float* v     = u + 1024;          // 8192
  float* acc   = v + 8192;          // 1
  float* out   = (float*)d_out;

  hipLaunchKernelGGL(kPrep, dim3(37), dim3(256), 0, stream, x, att, qq, tt, logmu, lognu, u, v, acc);
  hipLaunchKernelGGL(kGemmM, dim3(128, 16), dim3(256), 0, stream, x, qq, tt, M);
  for (int it = 0; it < OT_ITERS; ++it){
    hipLaunchKernelGGL(kUPass, dim3(1024), dim3(256), 0, stream, M, v, logmu, u);
    hipLaunchKernelGGL(kVPass, dim3(256), dim3(256), 0, stream, M, u, lognu, v);
  }
  hipLaunchKernelGGL(kFinal, dim3(256), dim3(256), 0, stream, x, att, M, u, v, acc);
  hipLaunchKernelGGL(kOut, dim3(1), dim3(1), 0, stream, acc, label, out);
}

// Round 2
// 14876.401 us; speedup vs baseline: 2.8825x; 2.8825x over previous
//
#include <hip/hip_runtime.h>
#include <math.h>

// Problem constants (fixed by reference: x (9,256,32,32) fp32, att (9,32,32) fp32)
#define MR 1024      // m = 32*32 query locations
#define NC 8192      // n = 8*32*32 target locations
#define NCH 256      // channels
#define OT_ITERS 1000
#define IMG_STRIDE 262144  // 256*1024 floats per image

__device__ inline float wredMax(float v){
#pragma unroll
  for (int m = 32; m >= 1; m >>= 1) v = fmaxf(v, __shfl_xor(v, m, 64));
  return v;
}
__device__ inline float wredSum(float v){
#pragma unroll
  for (int m = 32; m >= 1; m >>= 1) v += __shfl_xor(v, m, 64);
  return v;
}

// K1: squared norms qq/tt, log marginals, zero-init u,v,acc
__global__ __launch_bounds__(256) void kPrep(const float* __restrict__ x,
                                             const float* __restrict__ att,
                                             float* __restrict__ qq, float* __restrict__ tt,
                                             float* __restrict__ logmu, float* __restrict__ lognu,
                                             float* __restrict__ u, float* __restrict__ v,
                                             float* __restrict__ acc){
  int idx = blockIdx.x * 256 + threadIdx.x;
  if (idx < 9216){
    int img = idx >> 10, pos = idx & 1023;
    const float* p = x + img * IMG_STRIDE + pos;
    float s = 0.f;
#pragma unroll 8
    for (int c = 0; c < NCH; ++c){ float a = p[c * 1024]; s += a * a; }
    float lg = logf(att[idx]);
    if (img == 0){ qq[idx] = s;        logmu[idx] = lg; }
    else         { tt[idx - 1024] = s; lognu[idx - 1024] = lg; }
  }
  if (idx < MR) u[idx] = 0.f;
  if (idx < NC) v[idx] = 0.f;
  if (idx == 0) *acc = 0.f;
}

// K2: M[i][j] = qq[i] + tt[j] - 2 * Q_i . T_j   (A^T*B style, both stored c-major)
__global__ __launch_bounds__(256) void kGemmM(const float* __restrict__ x,
                                              const float* __restrict__ qq,
                                              const float* __restrict__ tt,
                                              float* __restrict__ M){
  __shared__ float As[16][68];
  __shared__ float Bs[16][68];
  int jb = blockIdx.x;              // 0..127 (column tiles of 64; never straddle image)
  int ib = blockIdx.y;              // 0..15
  int i0 = ib * 64;
  int j0 = jb * 64;
  int k  = j0 >> 10, p0 = j0 & 1023;
  const float* A = x + i0;
  const float* B = x + (1 + k) * IMG_STRIDE + p0;
  int tid = threadIdx.x;
  int lr = tid >> 4, lc = (tid & 15) * 4;
  int ty = tid >> 4, tx = tid & 15;
  float accv[4][4] = {};
  for (int kt = 0; kt < 16; ++kt){
    int c = kt * 16 + lr;
    float4 av = *(const float4*)(A + c * 1024 + lc);
    float4 bv = *(const float4*)(B + c * 1024 + lc);
    *(float4*)(&As[lr][lc]) = av;
    *(float4*)(&Bs[lr][lc]) = bv;
    __syncthreads();
#pragma unroll
    for (int kk = 0; kk < 16; ++kk){
      float4 a = *(const float4*)(&As[kk][ty * 4]);
      float4 b = *(const float4*)(&Bs[kk][tx * 4]);
      float ar[4] = {a.x, a.y, a.z, a.w};
      float br[4] = {b.x, b.y, b.z, b.w};
#pragma unroll
      for (int r = 0; r < 4; ++r)
#pragma unroll
        for (int cc = 0; cc < 4; ++cc) accv[r][cc] += ar[r] * br[cc];
    }
    __syncthreads();
  }
#pragma unroll
  for (int r = 0; r < 4; ++r){
    int i = i0 + ty * 4 + r;
    float qi = qq[i];
    float4 o;
    o.x = qi + tt[j0 + tx * 4 + 0] - 2.f * accv[r][0];
    o.y = qi + tt[j0 + tx * 4 + 1] - 2.f * accv[r][1];
    o.z = qi + tt[j0 + tx * 4 + 2] - 2.f * accv[r][2];
    o.w = qi + tt[j0 + tx * 4 + 3] - 2.f * accv[r][3];
    *(float4*)(M + (long)i * NC + j0 + tx * 4) = o;
  }
}

// K2b: one-time LDS-tiled transpose M (1024x8192) -> Mt (8192x1024)
__global__ __launch_bounds__(256) void kTrans(const float* __restrict__ M,
                                              float* __restrict__ Mt){
  __shared__ float tile[64][65];
  int i0 = blockIdx.y * 64;  // row tile (0..15)
  int j0 = blockIdx.x * 64;  // col tile (0..127)
  int t = threadIdx.x;
  int tc = t & 63, tr = t >> 6;
#pragma unroll
  for (int rr = 0; rr < 64; rr += 4)
    tile[rr + tr][tc] = M[(long)(i0 + rr + tr) * NC + j0 + tc];
  __syncthreads();
#pragma unroll
  for (int rr = 0; rr < 64; rr += 4)
    Mt[(long)(j0 + rr + tr) * MR + i0 + tc] = tile[tc][rr + tr];
}

// K3: u[i] = logmu[i] - LSE_j(M[i][j] + v[j]); one block per row, row in registers
__global__ __launch_bounds__(256) void kUPass(const float* __restrict__ M,
                                              const float* __restrict__ v,
                                              const float* __restrict__ logmu,
                                              float* __restrict__ u){
  int row = blockIdx.x;
  int tid = threadIdx.x;
  const float* Mr = M + (long)row * NC;
  float t[32];
  float mx = -INFINITY;
#pragma unroll
  for (int kb = 0; kb < 8; ++kb){
    int cidx = kb * 1024 + tid * 4;
    float4 mv = *(const float4*)(Mr + cidx);
    float4 vv = *(const float4*)(v + cidx);
    float t0 = mv.x + vv.x, t1 = mv.y + vv.y, t2 = mv.z + vv.z, t3 = mv.w + vv.w;
    t[kb * 4 + 0] = t0; t[kb * 4 + 1] = t1; t[kb * 4 + 2] = t2; t[kb * 4 + 3] = t3;
    mx = fmaxf(mx, fmaxf(fmaxf(t0, t1), fmaxf(t2, t3)));
  }
  __shared__ float redA[4], redB[4];
  int lane = tid & 63, wid = tid >> 6;
  float wm = wredMax(mx);
  if (lane == 0) redA[wid] = wm;
  __syncthreads();
  float bm = fmaxf(fmaxf(redA[0], redA[1]), fmaxf(redA[2], redA[3]));
  float s = 0.f;
#pragma unroll
  for (int i2 = 0; i2 < 32; ++i2) s += __expf(t[i2] - bm);
  float ws = wredSum(s);
  if (lane == 0) redB[wid] = ws;
  __syncthreads();
  if (tid == 0){
    float tot = redB[0] + redB[1] + redB[2] + redB[3];
    u[row] = logmu[row] - (bm + __logf(tot));
  }
}

// K4 (new): v[j] = lognu[j] - LSE_i(Mt[j][i] + u[i]); wave per column, row-major Mt
__global__ __launch_bounds__(256) void kVPassT(const float* __restrict__ Mt,
                                               const float* __restrict__ u,
                                               const float* __restrict__ lognu,
                                               float* __restrict__ v){
  __shared__ float ulds[1024];
  int t = threadIdx.x;
  *(float4*)(&ulds[t * 4]) = *(const float4*)(u + t * 4);
  __syncthreads();
  int w = t >> 6, lane = t & 63;
  int j = blockIdx.x * 4 + w;
  const float* R = Mt + (long)j * MR;
  float tv[16];
  float mx = -INFINITY;
#pragma unroll
  for (int q = 0; q < 4; ++q){
    int base = q * 256 + lane * 4;
    float4 mv = *(const float4*)(R + base);
    float4 uv = *(const float4*)(&ulds[base]);
    float t0 = mv.x + uv.x, t1 = mv.y + uv.y, t2 = mv.z + uv.z, t3 = mv.w + uv.w;
    tv[q * 4 + 0] = t0; tv[q * 4 + 1] = t1; tv[q * 4 + 2] = t2; tv[q * 4 + 3] = t3;
    mx = fmaxf(mx, fmaxf(fmaxf(t0, t1), fmaxf(t2, t3)));
  }
  mx = wredMax(mx);
  float s = 0.f;
#pragma unroll
  for (int q2 = 0; q2 < 16; ++q2) s += __expf(tv[q2] - mx);
  s = wredSum(s);
  if (lane == 0) v[j] = lognu[j] - (mx + __logf(s));
}

// K4-fallback (old): column-major pass over M, used only if ws too small for Mt
__global__ __launch_bounds__(256) void kVPass(const float* __restrict__ M,
                                              const float* __restrict__ u,
                                              const float* __restrict__ lognu,
                                              float* __restrict__ v){
  __shared__ float ulds[1024];
  __shared__ float pm[8][32];
  __shared__ float cm[32];
  __shared__ float ps[8][32];
  int tid = threadIdx.x;
  int j0 = blockIdx.x * 32;
  int c = tid & 31, rg = tid >> 5;
  { float4 uv = *(const float4*)(u + tid * 4); *(float4*)(&ulds[tid * 4]) = uv; }
  __syncthreads();
  const float* Mp = M + j0 + c;
  float mx = -INFINITY;
  for (int r = rg; r < 1024; r += 8){
    float tv = Mp[(long)r * NC] + ulds[r];
    mx = fmaxf(mx, tv);
  }
  pm[rg][c] = mx;
  __syncthreads();
  if (tid < 32){
    float a = pm[0][tid];
#pragma unroll
    for (int q = 1; q < 8; ++q) a = fmaxf(a, pm[q][tid]);
    cm[tid] = a;
  }
  __syncthreads();
  float cmc = cm[c];
  float s = 0.f;
  for (int r = rg; r < 1024; r += 8){
    float tv = Mp[(long)r * NC] + ulds[r];
    s += __expf(tv - cmc);
  }
  ps[rg][c] = s;
  __syncthreads();
  if (tid < 32){
    float a = 0.f;
#pragma unroll
    for (int q = 0; q < 8; ++q) a += ps[q][tid];
    int j = j0 + tid;
    v[j] = lognu[j] - (cm[tid] + __logf(a));
  }
}

// K5: o = P@T rows, diff = mu*Q - o, acc += sum_i ||diff_i||_2 ; 4 rows per block
__global__ __launch_bounds__(256) void kFinal(const float* __restrict__ x,
                                              const float* __restrict__ att,
                                              const float* __restrict__ M,
                                              const float* __restrict__ u,
                                              const float* __restrict__ v,
                                              float* __restrict__ acc){
  __shared__ float pch[4][256];
  __shared__ float redS[4];
  int tid = threadIdx.x;
  int r0 = blockIdx.x * 4;
  float u4[4];
#pragma unroll
  for (int rr = 0; rr < 4; ++rr) u4[rr] = u[r0 + rr];
  float o[4] = {0.f, 0.f, 0.f, 0.f};
  for (int jc = 0; jc < NC; jc += 256){
    float vv = v[jc + tid];
#pragma unroll
    for (int rr = 0; rr < 4; ++rr)
      pch[rr][tid] = __expf(M[(long)(r0 + rr) * NC + jc + tid] + u4[rr] + vv);
    __syncthreads();
    int k = jc >> 10;
    const float* Tp = x + (1 + k) * IMG_STRIDE + tid * 1024 + (jc & 1023);
    for (int jj = 0; jj < 256; jj += 4){
      float4 tv = *(const float4*)(Tp + jj);
      float tq[4] = {tv.x, tv.y, tv.z, tv.w};
#pragma unroll
      for (int q = 0; q < 4; ++q){
        o[0] += pch[0][jj + q] * tq[q];
        o[1] += pch[1][jj + q] * tq[q];
        o[2] += pch[2][jj + q] * tq[q];
        o[3] += pch[3][jj + q] * tq[q];
      }
    }
    __syncthreads();
  }
  int lane = tid & 63, wid = tid >> 6;
  float dtot = 0.f;
#pragma unroll
  for (int rr = 0; rr < 4; ++rr){
    float mu = att[r0 + rr];
    float qv = x[tid * 1024 + (r0 + rr)];
    float diff = mu * qv - o[rr];
    float wsum = wredSum(diff * diff);
    if (lane == 0) redS[wid] = wsum;
    __syncthreads();
    if (tid == 0) dtot += sqrtf(redS[0] + redS[1] + redS[2] + redS[3]);
    __syncthreads();
  }
  if (tid == 0) atomicAdd(acc, dtot);
}

// K6: apply label/margin, write scalar output
__global__ void kOut(const float* __restrict__ acc, const int* __restrict__ label,
                     float* __restrict__ out){
  if (threadIdx.x == 0 && blockIdx.x == 0){
    float d = *acc;
    out[0] = (*label) ? d : fmaxf(0.7f - d, 0.f);
  }
}

extern "C" void kernel_launch(void* const* d_in, const int* in_sizes, int n_in,
                              void* d_out, int out_size, void* d_ws, size_t ws_size,
                              hipStream_t stream){
  const float* x   = (const float*)d_in[0];
  const float* att = (const float*)d_in[1];
  const int* label = (const int*)d_in[2];
  float* W = (float*)d_ws;
  float* out = (float*)d_out;

  // Preferred layout (needs ~67.2 MB): M, Mt, then small arrays
  const size_t needMt = (size_t)(2 * 8388608 + 1024 + 8192 + 1024 + 8192 + 1024 + 8192 + 1) * 4;
  bool useMt = (ws_size >= needMt);

  float* M  = W;
  float* Mt = useMt ? (W + 8388608) : nullptr;
  float* qq    = useMt ? (W + 2 * 8388608) : (W + 8388608);
  float* tt    = qq + 1024;
  float* logmu = tt + 8192;
  float* lognu = logmu + 1024;
  float* u     = lognu + 8192;
  float* v     = u + 1024;
  float* acc   = v + 8192;

  hipLaunchKernelGGL(kPrep, dim3(37), dim3(256), 0, stream, x, att, qq, tt, logmu, lognu, u, v, acc);
  hipLaunchKernelGGL(kGemmM, dim3(128, 16), dim3(256), 0, stream, x, qq, tt, M);
  if (useMt){
    hipLaunchKernelGGL(kTrans, dim3(128, 16), dim3(256), 0, stream, M, Mt);
    for (int it = 0; it < OT_ITERS; ++it){
      hipLaunchKernelGGL(kUPass, dim3(1024), dim3(256), 0, stream, M, v, logmu, u);
      hipLaunchKernelGGL(kVPassT, dim3(2048), dim3(256), 0, stream, Mt, u, lognu, v);
    }
  } else {
    for (int it = 0; it < OT_ITERS; ++it){
      hipLaunchKernelGGL(kUPass, dim3(1024), dim3(256), 0, stream, M, v, logmu, u);
      hipLaunchKernelGGL(kVPass, dim3(256), dim3(256), 0, stream, M, u, lognu, v);
    }
  }
  hipLaunchKernelGGL(kFinal, dim3(256), dim3(256), 0, stream, x, att, M, u, v, acc);
  hipLaunchKernelGGL(kOut, dim3(1), dim3(1), 0, stream, acc, label, out);
}